// Round 1
// baseline (569.130 us; speedup 1.0000x reference)
//
#include <hip/hip_runtime.h>
#include <math.h>

#define RC2 25.0f

// Kernel 1: per-atom prep — 3x3 cell inverse (uniform, redundant per thread),
// fractional coords wrapped to [0,1) into ws, and the onehot output chunk.
__global__ __launch_bounds__(256) void prep_kernel(
    const float* __restrict__ coord,
    const float* __restrict__ cell,
    const int* __restrict__ elems,
    float* __restrict__ onehot,   // d_out chunk 0: (n,4)
    float* __restrict__ frac,     // ws: (n,3)
    int n)
{
    int i = blockIdx.x * blockDim.x + threadIdx.x;
    if (i >= n) return;

    float a = cell[0], b = cell[1], c = cell[2];
    float d = cell[3], e = cell[4], f = cell[5];
    float g = cell[6], h = cell[7], k = cell[8];
    float A =  (e * k - f * h);
    float B = -(d * k - f * g);
    float C =  (d * h - e * g);
    float det = a * A + b * B + c * C;
    float inv = 1.0f / det;
    // inverse of row-major cell
    float m00 = A * inv,              m01 = -(b * k - c * h) * inv, m02 =  (b * f - c * e) * inv;
    float m10 = B * inv,              m11 =  (a * k - c * g) * inv, m12 = -(a * f - c * d) * inv;
    float m20 = C * inv,              m21 = -(a * h - b * g) * inv, m22 =  (a * e - b * d) * inv;

    float x = coord[i * 3 + 0];
    float y = coord[i * 3 + 1];
    float z = coord[i * 3 + 2];
    // frac = coord @ h_inv  (row-vector times matrix)
    float fx = x * m00 + y * m10 + z * m20;
    float fy = x * m01 + y * m11 + z * m21;
    float fz = x * m02 + y * m12 + z * m22;
    fx -= floorf(fx); fy -= floorf(fy); fz -= floorf(fz);
    frac[i * 3 + 0] = fx;
    frac[i * 3 + 1] = fy;
    frac[i * 3 + 2] = fz;

    int el = elems[i];
    onehot[i * 4 + 0] = (el == 1) ? 1.0f : 0.0f;
    onehot[i * 4 + 1] = (el == 6) ? 1.0f : 0.0f;
    onehot[i * 4 + 2] = (el == 7) ? 1.0f : 0.0f;
    onehot[i * 4 + 3] = (el == 8) ? 1.0f : 0.0f;
}

// Kernel 2: pair kernel. blockIdx.y = i (row). Each thread handles 4
// consecutive j: one float4 dist store + 3 float4 shift stores (16B aligned:
// j0 % 4 == 0 so (i*n + j0)*3 floats is 16B-aligned since n*3 = 18000 ≡ 0 mod 4).
__global__ __launch_bounds__(256) void pair_kernel(
    const float* __restrict__ frac,
    const float* __restrict__ cell,
    float* __restrict__ dist,    // (n,n)
    float* __restrict__ shift,   // (n,n,3)
    int n)
{
    int i  = blockIdx.y;
    int j0 = (blockIdx.x * blockDim.x + threadIdx.x) * 4;
    if (j0 >= n) return;

    // uniform cell (scalar loads)
    float c00 = cell[0], c01 = cell[1], c02 = cell[2];
    float c10 = cell[3], c11 = cell[4], c12 = cell[5];
    float c20 = cell[6], c21 = cell[7], c22 = cell[8];

    float fi0 = frac[i * 3 + 0];
    float fi1 = frac[i * 3 + 1];
    float fi2 = frac[i * 3 + 2];

    // 12 contiguous floats = frac for j0..j0+3 (16B aligned: j0*3*4 ≡ 0 mod 16... j0%4==0 → j0*12 bytes %16 may be 0 or 8; use two paths via float4 only when aligned)
    // j0 % 4 == 0 → j0*3 floats → j0*12 bytes; j0=4 → 48 bytes: aligned. j0 multiple of 4 → j0*12 multiple of 48 → multiple of 16. OK.
    const float4* fj4 = (const float4*)(frac + (size_t)j0 * 3);
    float4 va = fj4[0], vb = fj4[1], vc = fj4[2];
    float fj[4][3] = {
        {va.x, va.y, va.z},
        {va.w, vb.x, vb.y},
        {vb.z, vb.w, vc.x},
        {vc.y, vc.z, vc.w}
    };

    float4 dout;
    float* dof = (float*)&dout;
    float4 sh[3];
    float* shf = (float*)sh;

#pragma unroll
    for (int t = 0; t < 4; t++) {
        float d0 = fj[t][0] - fi0;
        float d1 = fj[t][1] - fi1;
        float d2 = fj[t][2] - fi2;
        float s0 = -rintf(d0);
        float s1 = -rintf(d1);
        float s2 = -rintf(d2);
        d0 += s0; d1 += s1; d2 += s2;
        float x = d0 * c00 + d1 * c10 + d2 * c20;
        float y = d0 * c01 + d1 * c11 + d2 * c21;
        float z = d0 * c02 + d1 * c12 + d2 * c22;
        float r2 = x * x + y * y + z * z;
        bool m = (r2 > 0.0f) && (r2 < RC2);
        dof[t] = m ? sqrtf(r2) : 0.0f;
        shf[t * 3 + 0] = s0;
        shf[t * 3 + 1] = s1;
        shf[t * 3 + 2] = s2;
    }

    *(float4*)(dist + (size_t)i * n + j0) = dout;
    float4* sp = (float4*)(shift + ((size_t)i * n + j0) * 3);
    sp[0] = sh[0];
    sp[1] = sh[1];
    sp[2] = sh[2];
}

extern "C" void kernel_launch(void* const* d_in, const int* in_sizes, int n_in,
                              void* d_out, int out_size, void* d_ws, size_t ws_size,
                              hipStream_t stream)
{
    const float* coord = (const float*)d_in[0];   // (n,3)
    const float* cell  = (const float*)d_in[1];   // (3,3)
    const int*   elems = (const int*)d_in[2];     // (n,)
    int n = in_sizes[2];                          // 6000

    float* out    = (float*)d_out;
    float* onehot = out;                               // n*4
    float* dist   = out + (size_t)n * 4;               // n*n
    float* shift  = out + (size_t)n * 4 + (size_t)n * n; // n*n*3

    float* frac = (float*)d_ws;                        // n*3 floats

    dim3 b1(256);
    dim3 g1((n + 255) / 256);
    prep_kernel<<<g1, b1, 0, stream>>>(coord, cell, elems, onehot, frac, n);

    // each thread: 4 j's; block covers 1024 j's
    dim3 b2(256);
    dim3 g2((n + 1023) / 1024, n);
    pair_kernel<<<g2, b2, 0, stream>>>(frac, cell, dist, shift, n);
}

// Round 2
// 566.508 us; speedup vs baseline: 1.0046x; 1.0046x over previous
//
#include <hip/hip_runtime.h>
#include <math.h>

#define RC2 25.0f

// Kernel 1: per-atom prep — 3x3 cell inverse (uniform, redundant per thread),
// fractional coords wrapped to [0,1) into ws, and the onehot output chunk.
__global__ __launch_bounds__(256) void prep_kernel(
    const float* __restrict__ coord,
    const float* __restrict__ cell,
    const int* __restrict__ elems,
    float* __restrict__ onehot,   // d_out chunk 0: (n,4)
    float* __restrict__ frac,     // ws: (n,3)
    int n)
{
    int i = blockIdx.x * blockDim.x + threadIdx.x;
    if (i >= n) return;

    float a = cell[0], b = cell[1], c = cell[2];
    float d = cell[3], e = cell[4], f = cell[5];
    float g = cell[6], h = cell[7], k = cell[8];
    float A =  (e * k - f * h);
    float B = -(d * k - f * g);
    float C =  (d * h - e * g);
    float det = a * A + b * B + c * C;
    float inv = 1.0f / det;
    float m00 = A * inv,              m01 = -(b * k - c * h) * inv, m02 =  (b * f - c * e) * inv;
    float m10 = B * inv,              m11 =  (a * k - c * g) * inv, m12 = -(a * f - c * d) * inv;
    float m20 = C * inv,              m21 = -(a * h - b * g) * inv, m22 =  (a * e - b * d) * inv;

    float x = coord[i * 3 + 0];
    float y = coord[i * 3 + 1];
    float z = coord[i * 3 + 2];
    float fx = x * m00 + y * m10 + z * m20;
    float fy = x * m01 + y * m11 + z * m21;
    float fz = x * m02 + y * m12 + z * m22;
    fx -= floorf(fx); fy -= floorf(fy); fz -= floorf(fz);
    frac[i * 3 + 0] = fx;
    frac[i * 3 + 1] = fy;
    frac[i * 3 + 2] = fz;

    int el = elems[i];
    onehot[i * 4 + 0] = (el == 1) ? 1.0f : 0.0f;
    onehot[i * 4 + 1] = (el == 6) ? 1.0f : 0.0f;
    onehot[i * 4 + 2] = (el == 7) ? 1.0f : 0.0f;
    onehot[i * 4 + 3] = (el == 8) ? 1.0f : 0.0f;
}

// Kernel 2: pair kernel. blockIdx.y = i (row); block covers 1024 consecutive j.
// Each thread computes 4 consecutive j. Dist stored directly (wave-contiguous
// float4). Shift values staged in LDS (exact final interleaved (j,3) layout),
// then written out as fully lane-contiguous float4 stores — every global store
// instruction covers a contiguous 1KB/wave span, matching the fill-kernel
// pattern that sustains 6.3 TB/s.
__global__ __launch_bounds__(256) void pair_kernel(
    const float* __restrict__ frac,
    const float* __restrict__ cell,
    float* __restrict__ dist,    // (n,n)
    float* __restrict__ shift,   // (n,n,3)
    int n)
{
    __shared__ float sh_lds[1024 * 3];   // 12 KB: shift chunk in final layout

    const int i  = blockIdx.y;
    const int J0 = blockIdx.x * 1024;
    const int t  = threadIdx.x;
    const int j0 = J0 + t * 4;

    if (j0 < n) {
        // uniform cell (scalar loads)
        float c00 = cell[0], c01 = cell[1], c02 = cell[2];
        float c10 = cell[3], c11 = cell[4], c12 = cell[5];
        float c20 = cell[6], c21 = cell[7], c22 = cell[8];

        float fi0 = frac[i * 3 + 0];
        float fi1 = frac[i * 3 + 1];
        float fi2 = frac[i * 3 + 2];

        // 12 contiguous floats = frac for j0..j0+3 (j0%4==0 -> 48B-aligned)
        const float4* fj4 = (const float4*)(frac + (size_t)j0 * 3);
        float4 va = fj4[0], vb = fj4[1], vc = fj4[2];
        float fj[4][3] = {
            {va.x, va.y, va.z},
            {va.w, vb.x, vb.y},
            {vb.z, vb.w, vc.x},
            {vc.y, vc.z, vc.w}
        };

        float4 dout;
        float* dof = (float*)&dout;
        float4 sh[3];
        float* shf = (float*)sh;

#pragma unroll
        for (int q = 0; q < 4; q++) {
            float d0 = fj[q][0] - fi0;
            float d1 = fj[q][1] - fi1;
            float d2 = fj[q][2] - fi2;
            float s0 = -rintf(d0);
            float s1 = -rintf(d1);
            float s2 = -rintf(d2);
            d0 += s0; d1 += s1; d2 += s2;
            float x = d0 * c00 + d1 * c10 + d2 * c20;
            float y = d0 * c01 + d1 * c11 + d2 * c21;
            float z = d0 * c02 + d1 * c12 + d2 * c22;
            float r2 = x * x + y * y + z * z;
            bool m = (r2 > 0.0f) && (r2 < RC2);
            dof[q] = m ? sqrtf(r2) : 0.0f;
            shf[q * 3 + 0] = s0;
            shf[q * 3 + 1] = s1;
            shf[q * 3 + 2] = s2;
        }

        // dist: wave-contiguous float4 store
        *(float4*)(dist + (size_t)i * n + j0) = dout;

        // shift -> LDS in final layout (3x ds_write_b128, 48B lane stride)
        float4* lp = (float4*)(sh_lds + t * 12);
        lp[0] = sh[0];
        lp[1] = sh[1];
        lp[2] = sh[2];
    }

    __syncthreads();

    // Coalesced writeout of the shift chunk: len*3 floats, contiguous.
    const int len = min(1024, n - J0);        // n % 4 == 0 -> len % 4 == 0
    const int nf4 = (len * 3) >> 2;           // float4 count (divisible evenly)
    const float4* ls = (const float4*)sh_lds;
    float4* gp = (float4*)(shift + ((size_t)i * n + J0) * 3);  // 16B aligned
#pragma unroll
    for (int k = 0; k < 3; k++) {
        int q = k * 256 + t;
        if (q < nf4) gp[q] = ls[q];
    }
}

extern "C" void kernel_launch(void* const* d_in, const int* in_sizes, int n_in,
                              void* d_out, int out_size, void* d_ws, size_t ws_size,
                              hipStream_t stream)
{
    const float* coord = (const float*)d_in[0];   // (n,3)
    const float* cell  = (const float*)d_in[1];   // (3,3)
    const int*   elems = (const int*)d_in[2];     // (n,)
    int n = in_sizes[2];                          // 6000

    float* out    = (float*)d_out;
    float* onehot = out;                                  // n*4
    float* dist   = out + (size_t)n * 4;                  // n*n
    float* shift  = out + (size_t)n * 4 + (size_t)n * n;  // n*n*3

    float* frac = (float*)d_ws;                           // n*3 floats

    dim3 b1(256);
    dim3 g1((n + 255) / 256);
    prep_kernel<<<g1, b1, 0, stream>>>(coord, cell, elems, onehot, frac, n);

    dim3 b2(256);
    dim3 g2((n + 1023) / 1024, n);
    pair_kernel<<<g2, b2, 0, stream>>>(frac, cell, dist, shift, n);
}

// Round 4
// 558.238 us; speedup vs baseline: 1.0195x; 1.0148x over previous
//
#include <hip/hip_runtime.h>
#include <math.h>

#define RC2 25.0f

// Native clang vector type — required by __builtin_nontemporal_store
// (HIP's float4 is a struct and is rejected).
typedef float f32x4 __attribute__((ext_vector_type(4)));

// Kernel 1: per-atom prep — 3x3 cell inverse (uniform, redundant per thread),
// fractional coords wrapped to [0,1) into ws, and the onehot output chunk.
__global__ __launch_bounds__(256) void prep_kernel(
    const float* __restrict__ coord,
    const float* __restrict__ cell,
    const int* __restrict__ elems,
    float* __restrict__ onehot,   // d_out chunk 0: (n,4)
    float* __restrict__ frac,     // ws: (n,3)
    int n)
{
    int i = blockIdx.x * blockDim.x + threadIdx.x;
    if (i >= n) return;

    float a = cell[0], b = cell[1], c = cell[2];
    float d = cell[3], e = cell[4], f = cell[5];
    float g = cell[6], h = cell[7], k = cell[8];
    float A =  (e * k - f * h);
    float B = -(d * k - f * g);
    float C =  (d * h - e * g);
    float det = a * A + b * B + c * C;
    float inv = 1.0f / det;
    float m00 = A * inv,              m01 = -(b * k - c * h) * inv, m02 =  (b * f - c * e) * inv;
    float m10 = B * inv,              m11 =  (a * k - c * g) * inv, m12 = -(a * f - c * d) * inv;
    float m20 = C * inv,              m21 = -(a * h - b * g) * inv, m22 =  (a * e - b * d) * inv;

    float x = coord[i * 3 + 0];
    float y = coord[i * 3 + 1];
    float z = coord[i * 3 + 2];
    float fx = x * m00 + y * m10 + z * m20;
    float fy = x * m01 + y * m11 + z * m21;
    float fz = x * m02 + y * m12 + z * m22;
    fx -= floorf(fx); fy -= floorf(fy); fz -= floorf(fz);
    frac[i * 3 + 0] = fx;
    frac[i * 3 + 1] = fy;
    frac[i * 3 + 2] = fz;

    int el = elems[i];
    f32x4 oh;
    oh.x = (el == 1) ? 1.0f : 0.0f;
    oh.y = (el == 6) ? 1.0f : 0.0f;
    oh.z = (el == 7) ? 1.0f : 0.0f;
    oh.w = (el == 8) ? 1.0f : 0.0f;
    __builtin_nontemporal_store(oh, (f32x4*)(onehot + (size_t)i * 4));
}

// Kernel 2: pair kernel. blockIdx.y = i (row); block covers 1024 consecutive j.
// Each thread computes 4 consecutive j. Dist stored directly (wave-contiguous
// float4, nt). Shift values staged in LDS in final layout, written out as
// lane-contiguous nontemporal float4 stores. nt bypasses the L2
// write-allocate/RFO path (theory: poisoned output lines were being fetched
// from HBM before overwrite, ~doubling HBM traffic).
__global__ __launch_bounds__(256) void pair_kernel(
    const float* __restrict__ frac,
    const float* __restrict__ cell,
    float* __restrict__ dist,    // (n,n)
    float* __restrict__ shift,   // (n,n,3)
    int n)
{
    __shared__ float sh_lds[1024 * 3];   // 12 KB: shift chunk in final layout

    const int i  = blockIdx.y;
    const int J0 = blockIdx.x * 1024;
    const int t  = threadIdx.x;
    const int j0 = J0 + t * 4;

    if (j0 < n) {
        // uniform cell (scalar loads)
        float c00 = cell[0], c01 = cell[1], c02 = cell[2];
        float c10 = cell[3], c11 = cell[4], c12 = cell[5];
        float c20 = cell[6], c21 = cell[7], c22 = cell[8];

        float fi0 = frac[i * 3 + 0];
        float fi1 = frac[i * 3 + 1];
        float fi2 = frac[i * 3 + 2];

        // 12 contiguous floats = frac for j0..j0+3 (j0%4==0 -> 48B-aligned)
        const float4* fj4 = (const float4*)(frac + (size_t)j0 * 3);
        float4 va = fj4[0], vb = fj4[1], vc = fj4[2];
        float fj[4][3] = {
            {va.x, va.y, va.z},
            {va.w, vb.x, vb.y},
            {vb.z, vb.w, vc.x},
            {vc.y, vc.z, vc.w}
        };

        f32x4 dout;
        float4 sh[3];
        float* shf = (float*)sh;

#pragma unroll
        for (int q = 0; q < 4; q++) {
            float d0 = fj[q][0] - fi0;
            float d1 = fj[q][1] - fi1;
            float d2 = fj[q][2] - fi2;
            float s0 = -rintf(d0);
            float s1 = -rintf(d1);
            float s2 = -rintf(d2);
            d0 += s0; d1 += s1; d2 += s2;
            float x = d0 * c00 + d1 * c10 + d2 * c20;
            float y = d0 * c01 + d1 * c11 + d2 * c21;
            float z = d0 * c02 + d1 * c12 + d2 * c22;
            float r2 = x * x + y * y + z * z;
            bool m = (r2 > 0.0f) && (r2 < RC2);
            dout[q] = m ? sqrtf(r2) : 0.0f;
            shf[q * 3 + 0] = s0;
            shf[q * 3 + 1] = s1;
            shf[q * 3 + 2] = s2;
        }

        // dist: wave-contiguous nontemporal float4 store
        __builtin_nontemporal_store(dout, (f32x4*)(dist + (size_t)i * n + j0));

        // shift -> LDS in final layout (3x ds_write_b128, 48B lane stride)
        float4* lp = (float4*)(sh_lds + t * 12);
        lp[0] = sh[0];
        lp[1] = sh[1];
        lp[2] = sh[2];
    }

    __syncthreads();

    // Coalesced nontemporal writeout of the shift chunk: len*3 floats.
    const int len = min(1024, n - J0);        // n % 4 == 0 -> len % 4 == 0
    const int nf4 = (len * 3) >> 2;           // float4 count
    const f32x4* ls = (const f32x4*)sh_lds;
    f32x4* gp = (f32x4*)(shift + ((size_t)i * n + J0) * 3);  // 16B aligned
#pragma unroll
    for (int k = 0; k < 3; k++) {
        int q = k * 256 + t;
        if (q < nf4) __builtin_nontemporal_store(ls[q], gp + q);
    }
}

extern "C" void kernel_launch(void* const* d_in, const int* in_sizes, int n_in,
                              void* d_out, int out_size, void* d_ws, size_t ws_size,
                              hipStream_t stream)
{
    const float* coord = (const float*)d_in[0];   // (n,3)
    const float* cell  = (const float*)d_in[1];   // (3,3)
    const int*   elems = (const int*)d_in[2];     // (n,)
    int n = in_sizes[2];                          // 6000

    float* out    = (float*)d_out;
    float* onehot = out;                                  // n*4
    float* dist   = out + (size_t)n * 4;                  // n*n
    float* shift  = out + (size_t)n * 4 + (size_t)n * n;  // n*n*3

    float* frac = (float*)d_ws;                           // n*3 floats

    dim3 b1(256);
    dim3 g1((n + 255) / 256);
    prep_kernel<<<g1, b1, 0, stream>>>(coord, cell, elems, onehot, frac, n);

    dim3 b2(256);
    dim3 g2((n + 1023) / 1024, n);
    pair_kernel<<<g2, b2, 0, stream>>>(frac, cell, dist, shift, n);
}